// Round 5
// baseline (124.808 us; speedup 1.0000x reference)
//
#include <hip/hip_runtime.h>
#include <math.h>

// Problem constants
#define BB 4096      // batch
#define NE 8         // experts
#define NP 256       // patches
#define NK 16        // patch dim
#define NF 64        // filter size
#define ROW 4096     // NP*NK floats per batch row
#define NBLK 1024    // blocks (4 rows each)

#define POISON 0xAAAAAAAAu  // harness re-poisons d_ws to 0xAA bytes each call

// ws float layout:
//   [0, 16384)  part[block][i]: i<8 -> h_e partial, i>=8 -> mask_e partial
//   [16384]     completion counter (unsigned; starts at POISON or 0)
#define WS_P   0
#define WS_CNT 16384

// Single fused kernel. One batch row per wave, 4 waves/block.
// Loss reduction: per-block partials go to ws via RELAXED agent-scope stores
// (write-through to coherence point, NO buffer_wbl2 -- R2's regression came
// from RELEASE-scope ops emitting per-block L2 writebacks). __syncthreads()
// emits s_waitcnt vmcnt(0) before s_barrier (m97-verified), so the partials
// are at the coherence point before the counter RMW. Last block re-reads them
// with relaxed agent-scope loads (coherence-point reads).
__global__ __launch_bounds__(256, 4) void main_kernel(const float* __restrict__ x,
                                                      const float* __restrict__ noise,
                                                      const float* __restrict__ gw,
                                                      const float* __restrict__ gb,
                                                      const float* __restrict__ ew,
                                                      const float* __restrict__ eb,
                                                      float* __restrict__ out,
                                                      float* __restrict__ ws) {
    __shared__ float hacc[8];
    __shared__ float macc[8];
    __shared__ unsigned old_sh;
    int tid = threadIdx.x;
    if (tid < 8) { hacc[tid] = 0.f; macc[tid] = 0.f; }
    __syncthreads();

    int wave = tid >> 6;
    int lane = tid & 63;
    int b = blockIdx.x * 4 + wave;

    // --- row reduction: s[b,k] = sum_p x[b, p*16+k] ---
    const float4* xb = (const float4*)(x + (size_t)b * ROW);
    float4 v[16];
#pragma unroll
    for (int t = 0; t < 16; ++t) v[t] = xb[lane + 64 * t];
#pragma unroll
    for (int st = 8; st >= 1; st >>= 1) {
#pragma unroll
        for (int t = 0; t < st; ++t) {
            v[t].x += v[t + st].x; v[t].y += v[t + st].y;
            v[t].z += v[t + st].z; v[t].w += v[t + st].w;
        }
    }
    float4 acc = v[0];
#pragma unroll
    for (int m = 4; m <= 32; m <<= 1) {
        acc.x += __shfl_xor(acc.x, m);
        acc.y += __shfl_xor(acc.y, m);
        acc.z += __shfl_xor(acc.z, m);
        acc.w += __shfl_xor(acc.w, m);
    }
    float s[16];
#pragma unroll
    for (int q = 0; q < 4; ++q) {
        s[4 * q + 0] = __shfl(acc.x, q);
        s[4 * q + 1] = __shfl(acc.y, q);
        s[4 * q + 2] = __shfl(acc.z, q);
        s[4 * q + 3] = __shfl(acc.w, q);
    }

    // --- gating: lanes 0..7 compute h[b,e] for e=lane ---
    float hv = -3.0e38f;
    if (lane < 8) {
        const float* gwr = gw + lane * NK;
        float d = 0.f;
#pragma unroll
        for (int k = 0; k < NK; ++k) d += s[k] * gwr[k];
        hv = d + 256.f * gb[lane] + noise[b];
    }
    // argmax (first-index tie-break) within lanes 0..7
    float mv = hv;
    int mi = lane & 7;
#pragma unroll
    for (int m = 1; m <= 4; m <<= 1) {
        float ov = __shfl_xor(mv, m);
        int oi = __shfl_xor(mi, m);
        if (ov > mv || (ov == mv && oi < mi)) { mv = ov; mi = oi; }
    }
    mv = __shfl(mv, 0);
    mi = __shfl(mi, 0);

    // --- expert output from ew[mi] (L2-hot: ew is 512 KB total) ---
    const float4* ewr = (const float4*)(ew + (size_t)mi * (128 * 16));
    float4 c0[4], c1[4];
#pragma unroll
    for (int q = 0; q < 4; ++q) {
        c0[q] = ewr[lane * 4 + q];          // channel lane (j=0)
        c1[q] = ewr[(64 + lane) * 4 + q];   // channel 64+lane (j=1)
    }
    float o0 = 0.f, o1 = 0.f;
#pragma unroll
    for (int q = 0; q < 4; ++q) {
        o0 += s[4*q+0]*c0[q].x + s[4*q+1]*c0[q].y + s[4*q+2]*c0[q].z + s[4*q+3]*c0[q].w;
        o1 += s[4*q+0]*c1[q].x + s[4*q+1]*c1[q].y + s[4*q+2]*c1[q].z + s[4*q+3]*c1[q].w;
    }
    o0 += 256.f * eb[mi * 128 + lane];
    o1 += 256.f * eb[mi * 128 + 64 + lane];
#pragma unroll
    for (int m = 1; m <= 32; m <<= 1) {
        o0 += __shfl_xor(o0, m);
        o1 += __shfl_xor(o1, m);
    }
    if (lane == 0) {
        out[b * 2 + 0] = mv * o0;
        out[b * 2 + 1] = mv * o1;
    }

    if (lane < 8) {
        float mk = (lane == mi) ? 1.f : 0.f;
        out[2 * BB + b * 8 + lane] = mk;   // mask output
        atomicAdd(&hacc[lane], hv);
        atomicAdd(&macc[lane], mk);
    }
    __syncthreads();

    // --- partials -> ws at coherence point (relaxed agent stores, no wbl2) ---
    float* part = ws + WS_P;
    if (tid < 16) {
        float vp = (tid < 8) ? hacc[tid] : macc[tid - 8];
        __hip_atomic_store(&part[blockIdx.x * 16 + tid], vp,
                           __ATOMIC_RELAXED, __HIP_MEMORY_SCOPE_AGENT);
    }
    __syncthreads();  // s_waitcnt vmcnt(0) before s_barrier -> stores retired

    if (tid == 0) {
        unsigned* cnt = (unsigned*)(ws + WS_CNT);
        old_sh = __hip_atomic_fetch_add(cnt, 1u, __ATOMIC_RELAXED,
                                        __HIP_MEMORY_SCOPE_AGENT);
    }
    __syncthreads();
    unsigned old = old_sh;
    // last-block detection for both possible ws init states (0xAA poison / 0);
    // the two observed-value windows are disjoint, exactly one block matches
    bool last = (old == POISON + (NBLK - 1u)) || (old == NBLK - 1u);

    if (last) {
        __shared__ float red[16][17];
        int e = tid & 15, c = tid >> 4;  // 16 chunks of 64 blocks
        float sum = 0.f;
        for (int blk = c; blk < NBLK; blk += 16)
            sum += __hip_atomic_load(&part[blk * 16 + e],
                                     __ATOMIC_RELAXED, __HIP_MEMORY_SCOPE_AGENT);
        red[c][e] = sum;
        __syncthreads();
        if (tid == 0) {
            float hs[8], ms[8];
#pragma unroll
            for (int e2 = 0; e2 < 8; ++e2) { hs[e2] = 0.f; ms[e2] = 0.f; }
            for (int c2 = 0; c2 < 16; ++c2) {
#pragma unroll
                for (int e2 = 0; e2 < 8; ++e2) {
                    hs[e2] += red[c2][e2];
                    ms[e2] += red[c2][8 + e2];
                }
            }
            float loss = 0.f;
#pragma unroll
            for (int e2 = 0; e2 < 8; ++e2)
                loss += (hs[e2] / 4096.f) * (ms[e2] / 4096.f);
            out[2 * BB + 8 * BB] = loss * 8.f;  // index 40960
        }
    }
}

extern "C" void kernel_launch(void* const* d_in, const int* in_sizes, int n_in,
                              void* d_out, int out_size, void* d_ws, size_t ws_size,
                              hipStream_t stream) {
    const float* x     = (const float*)d_in[0];
    const float* noise = (const float*)d_in[1];
    const float* gw    = (const float*)d_in[2];
    const float* gb    = (const float*)d_in[3];
    const float* ew    = (const float*)d_in[4];
    const float* eb    = (const float*)d_in[5];
    float* out = (float*)d_out;
    float* ws  = (float*)d_ws;

    main_kernel<<<NBLK, 256, 0, stream>>>(x, noise, gw, gb, ew, eb, out, ws);
}

// Round 7
// 118.202 us; speedup vs baseline: 1.0559x; 1.0559x over previous
//
#include <hip/hip_runtime.h>
#include <math.h>

// Problem constants
#define BB 4096      // batch
#define NE 8         // experts
#define NP 256       // patches
#define NK 16        // patch dim
#define NF 64        // filter size
#define ROW 4096     // NP*KK floats per batch row
#define NBLK 1024    // main-kernel blocks (4 rows each)

// ws float layout:
//   [0, 8192)     hpart[block][e]   (1024 blocks x 8 experts)
//   [8192, 16384) mpart[block][e]
#define WS_H 0
#define WS_M 8192

// native vector type: __builtin_nontemporal_load rejects HIP_vector_type
// structs but accepts clang ext_vector types.
typedef float vf4 __attribute__((ext_vector_type(4)));

// R4 structure (best known: 111.5us). R5 lesson: ANY in-kernel cross-block
// completion scheme (release fences / relaxed agent atomics) costs 18-65us
// more than a separate 1-block loss dispatch -- kernel-boundary release is
// the cheapest device-wide visibility on gfx950. Single change vs R4:
// non-temporal x loads (no-allocate) so our 64MB stream doesn't evict the
// harness's ~268MB of dirty poison lines from L2/L3 ahead of need.
__global__ __launch_bounds__(256, 4) void main_kernel(const float* __restrict__ x,
                                                      const float* __restrict__ noise,
                                                      const float* __restrict__ gw,
                                                      const float* __restrict__ gb,
                                                      const float* __restrict__ ew,
                                                      const float* __restrict__ eb,
                                                      float* __restrict__ out,
                                                      float* __restrict__ hpart,
                                                      float* __restrict__ mpart) {
    __shared__ float hacc[8];
    __shared__ float macc[8];
    int tid = threadIdx.x;
    if (tid < 8) { hacc[tid] = 0.f; macc[tid] = 0.f; }
    __syncthreads();

    int wave = tid >> 6;
    int lane = tid & 63;
    int b = blockIdx.x * 4 + wave;

    // --- row reduction: s[b,k] = sum_p x[b, p*16+k] ---
    const vf4* xb = (const vf4*)(x + (size_t)b * ROW);
    vf4 v[16];
#pragma unroll
    for (int t = 0; t < 16; ++t)
        v[t] = __builtin_nontemporal_load(&xb[lane + 64 * t]);
#pragma unroll
    for (int st = 8; st >= 1; st >>= 1) {
#pragma unroll
        for (int t = 0; t < st; ++t) v[t] += v[t + st];
    }
    vf4 acc = v[0];
    // lanes sharing (lane&3) hold the same 4 buckets; butterfly-reduce
#pragma unroll
    for (int m = 4; m <= 32; m <<= 1) {
        acc.x += __shfl_xor(acc.x, m);
        acc.y += __shfl_xor(acc.y, m);
        acc.z += __shfl_xor(acc.z, m);
        acc.w += __shfl_xor(acc.w, m);
    }
    // broadcast all 16 bucket sums to every lane (lane q<4 holds buckets 4q..4q+3)
    float s[16];
#pragma unroll
    for (int q = 0; q < 4; ++q) {
        s[4 * q + 0] = __shfl(acc.x, q);
        s[4 * q + 1] = __shfl(acc.y, q);
        s[4 * q + 2] = __shfl(acc.z, q);
        s[4 * q + 3] = __shfl(acc.w, q);
    }

    // --- gating: lanes 0..7 compute h[b,e] for e=lane ---
    float hv = -3.0e38f;
    if (lane < 8) {
        const float* gwr = gw + lane * NK;
        float d = 0.f;
#pragma unroll
        for (int k = 0; k < NK; ++k) d += s[k] * gwr[k];
        hv = d + 256.f * gb[lane] + noise[b];
    }
    // argmax (first-index tie-break) within lanes 0..7
    float mv = hv;
    int mi = lane & 7;
#pragma unroll
    for (int m = 1; m <= 4; m <<= 1) {
        float ov = __shfl_xor(mv, m);
        int oi = __shfl_xor(mi, m);
        if (ov > mv || (ov == mv && oi < mi)) { mv = ov; mi = oi; }
    }
    mv = __shfl(mv, 0);
    mi = __shfl(mi, 0);

    // --- expert output from ew[mi] (512 KB total -> L2-resident; keep cached) ---
    const vf4* ewr = (const vf4*)(ew + (size_t)mi * (128 * 16));
    vf4 c0[4], c1[4];
#pragma unroll
    for (int q = 0; q < 4; ++q) {
        c0[q] = ewr[lane * 4 + q];          // channel lane (j=0)
        c1[q] = ewr[(64 + lane) * 4 + q];   // channel 64+lane (j=1)
    }
    float o0 = 0.f, o1 = 0.f;
#pragma unroll
    for (int q = 0; q < 4; ++q) {
        o0 += s[4*q+0]*c0[q].x + s[4*q+1]*c0[q].y + s[4*q+2]*c0[q].z + s[4*q+3]*c0[q].w;
        o1 += s[4*q+0]*c1[q].x + s[4*q+1]*c1[q].y + s[4*q+2]*c1[q].z + s[4*q+3]*c1[q].w;
    }
    o0 += 256.f * eb[mi * 128 + lane];
    o1 += 256.f * eb[mi * 128 + 64 + lane];
#pragma unroll
    for (int m = 1; m <= 32; m <<= 1) {
        o0 += __shfl_xor(o0, m);
        o1 += __shfl_xor(o1, m);
    }
    if (lane == 0) {
        out[b * 2 + 0] = mv * o0;
        out[b * 2 + 1] = mv * o1;
    }

    if (lane < 8) {
        float mk = (lane == mi) ? 1.f : 0.f;
        out[2 * BB + b * 8 + lane] = mk;   // mask output
        atomicAdd(&hacc[lane], hv);
        atomicAdd(&macc[lane], mk);
    }
    __syncthreads();
    // plain stores; loss kernel is a later dispatch -> end-of-kernel release
    // gives device-wide visibility without per-block fences (R2/R5 lessons)
    if (tid < 8) {
        hpart[blockIdx.x * 8 + tid] = hacc[tid];
        mpart[blockIdx.x * 8 + tid] = macc[tid];
    }
}

__global__ __launch_bounds__(256) void loss_kernel(const float* __restrict__ hpart,
                                                   const float* __restrict__ mpart,
                                                   float* __restrict__ out) {
    __shared__ float hs[256], ms[256];
    int t = threadIdx.x;
    int e = t & 7, c = t >> 3;  // 32 chunks of 32 blocks
    float hsum = 0.f, msum = 0.f;
    for (int i = c; i < NBLK; i += 32) {
        hsum += hpart[i * 8 + e];
        msum += mpart[i * 8 + e];
    }
    hs[t] = hsum;
    ms[t] = msum;
    __syncthreads();
    if (t < 8) {
        float hh = 0.f, mm = 0.f;
        for (int c2 = 0; c2 < 32; ++c2) { hh += hs[c2 * 8 + t]; mm += ms[c2 * 8 + t]; }
        hs[t] = hh;
        ms[t] = mm;
    }
    __syncthreads();
    if (t == 0) {
        float loss = 0.f;
        for (int e2 = 0; e2 < 8; ++e2)
            loss += (hs[e2] / 4096.f) * (ms[e2] / 4096.f);
        out[2 * BB + 8 * BB] = loss * 8.f;  // index 40960
    }
}

extern "C" void kernel_launch(void* const* d_in, const int* in_sizes, int n_in,
                              void* d_out, int out_size, void* d_ws, size_t ws_size,
                              hipStream_t stream) {
    const float* x     = (const float*)d_in[0];
    const float* noise = (const float*)d_in[1];
    const float* gw    = (const float*)d_in[2];
    const float* gb    = (const float*)d_in[3];
    const float* ew    = (const float*)d_in[4];
    const float* eb    = (const float*)d_in[5];
    float* out = (float*)d_out;
    float* ws  = (float*)d_ws;

    main_kernel<<<NBLK, 256, 0, stream>>>(x, noise, gw, gb, ew, eb, out,
                                          ws + WS_H, ws + WS_M);
    loss_kernel<<<1, 256, 0, stream>>>(ws + WS_H, ws + WS_M, out);
}

// Round 8
// 111.119 us; speedup vs baseline: 1.1232x; 1.0637x over previous
//
#include <hip/hip_runtime.h>
#include <math.h>

// Problem constants
#define BB 4096      // batch
#define NE 8         // experts
#define NP 256       // patches
#define NK 16        // patch dim
#define NF 64        // filter size
#define ROW 4096     // NP*NK floats per batch row
#define NBLK 1024    // main-kernel blocks (4 rows each)

// ws float layout:
//   [0, 8192)     hpart[block][e]   (1024 blocks x 8 experts)
//   [8192, 16384) mpart[block][e]
#define WS_H 0
#define WS_M 8192

// FINAL = R4 structure (best measured: 111.5us headline; ~12us controllable).
// Session ledger:
//  - 3-kernel (R1, 122) -> drop prep, in-wave expert compute (R4, 111.5): WIN
//  - single-kernel fusion: release fences (R2, 195) / relaxed agent atomics
//    (R5, 124.8): REGRESSED -- cross-block visibility via kernel-boundary
//    release + tiny 2nd dispatch is cheapest on gfx950 (per-XCD L2s make any
//    in-kernel agent-scope traffic expensive).
//  - nontemporal x loads (R7, 118.2): REGRESSED -- x is ~50% L3-resident
//    (FETCH=33MB of 64MB); nt forfeits those hits.
// Remaining floor: ~10.6us HBM read of x + ~2-4us dispatch overhead, inside a
// ~100us harness-reset-dominated timing window. Structural.
__global__ __launch_bounds__(256, 4) void main_kernel(const float* __restrict__ x,
                                                      const float* __restrict__ noise,
                                                      const float* __restrict__ gw,
                                                      const float* __restrict__ gb,
                                                      const float* __restrict__ ew,
                                                      const float* __restrict__ eb,
                                                      float* __restrict__ out,
                                                      float* __restrict__ hpart,
                                                      float* __restrict__ mpart) {
    __shared__ float hacc[8];
    __shared__ float macc[8];
    int tid = threadIdx.x;
    if (tid < 8) { hacc[tid] = 0.f; macc[tid] = 0.f; }
    __syncthreads();

    int wave = tid >> 6;
    int lane = tid & 63;
    int b = blockIdx.x * 4 + wave;

    // --- row reduction: s[b,k] = sum_p x[b, p*16+k] ---
    // All 16 float4 loads issued before any use -> 16 KB in flight per wave.
    const float4* xb = (const float4*)(x + (size_t)b * ROW);
    float4 v[16];
#pragma unroll
    for (int t = 0; t < 16; ++t) v[t] = xb[lane + 64 * t];
#pragma unroll
    for (int st = 8; st >= 1; st >>= 1) {
#pragma unroll
        for (int t = 0; t < st; ++t) {
            v[t].x += v[t + st].x; v[t].y += v[t + st].y;
            v[t].z += v[t + st].z; v[t].w += v[t + st].w;
        }
    }
    float4 acc = v[0];
    // lanes sharing (lane&3) hold the same 4 buckets; butterfly-reduce
#pragma unroll
    for (int m = 4; m <= 32; m <<= 1) {
        acc.x += __shfl_xor(acc.x, m);
        acc.y += __shfl_xor(acc.y, m);
        acc.z += __shfl_xor(acc.z, m);
        acc.w += __shfl_xor(acc.w, m);
    }
    // broadcast all 16 bucket sums to every lane (lane q<4 holds buckets 4q..4q+3)
    float s[16];
#pragma unroll
    for (int q = 0; q < 4; ++q) {
        s[4 * q + 0] = __shfl(acc.x, q);
        s[4 * q + 1] = __shfl(acc.y, q);
        s[4 * q + 2] = __shfl(acc.z, q);
        s[4 * q + 3] = __shfl(acc.w, q);
    }

    // --- gating: lanes 0..7 compute h[b,e] for e=lane ---
    float hv = -3.0e38f;
    if (lane < 8) {
        const float* gwr = gw + lane * NK;
        float d = 0.f;
#pragma unroll
        for (int k = 0; k < NK; ++k) d += s[k] * gwr[k];
        hv = d + 256.f * gb[lane] + noise[b];
    }
    // argmax (first-index tie-break) within lanes 0..7
    float mv = hv;
    int mi = lane & 7;
#pragma unroll
    for (int m = 1; m <= 4; m <<= 1) {
        float ov = __shfl_xor(mv, m);
        int oi = __shfl_xor(mi, m);
        if (ov > mv || (ov == mv && oi < mi)) { mv = ov; mi = oi; }
    }
    mv = __shfl(mv, 0);
    mi = __shfl(mi, 0);

    // --- expert output from ew[mi] (512 KB total -> L2/L3-resident) ---
    const float4* ewr = (const float4*)(ew + (size_t)mi * (128 * 16));
    float4 c0[4], c1[4];
#pragma unroll
    for (int q = 0; q < 4; ++q) {
        c0[q] = ewr[lane * 4 + q];          // channel lane (j=0)
        c1[q] = ewr[(64 + lane) * 4 + q];   // channel 64+lane (j=1)
    }
    float o0 = 0.f, o1 = 0.f;
#pragma unroll
    for (int q = 0; q < 4; ++q) {
        o0 += s[4*q+0]*c0[q].x + s[4*q+1]*c0[q].y + s[4*q+2]*c0[q].z + s[4*q+3]*c0[q].w;
        o1 += s[4*q+0]*c1[q].x + s[4*q+1]*c1[q].y + s[4*q+2]*c1[q].z + s[4*q+3]*c1[q].w;
    }
    o0 += 256.f * eb[mi * 128 + lane];
    o1 += 256.f * eb[mi * 128 + 64 + lane];
#pragma unroll
    for (int m = 1; m <= 32; m <<= 1) {
        o0 += __shfl_xor(o0, m);
        o1 += __shfl_xor(o1, m);
    }
    if (lane == 0) {
        out[b * 2 + 0] = mv * o0;
        out[b * 2 + 1] = mv * o1;
    }

    if (lane < 8) {
        float mk = (lane == mi) ? 1.f : 0.f;
        out[2 * BB + b * 8 + lane] = mk;   // mask output
        atomicAdd(&hacc[lane], hv);
        atomicAdd(&macc[lane], mk);
    }
    __syncthreads();
    // plain stores; loss kernel is a later dispatch -> end-of-kernel release
    // gives device-wide visibility without per-block fences (R2/R5 lessons)
    if (tid < 8) {
        hpart[blockIdx.x * 8 + tid] = hacc[tid];
        mpart[blockIdx.x * 8 + tid] = macc[tid];
    }
}

__global__ __launch_bounds__(256) void loss_kernel(const float* __restrict__ hpart,
                                                   const float* __restrict__ mpart,
                                                   float* __restrict__ out) {
    __shared__ float hs[256], ms[256];
    int t = threadIdx.x;
    int e = t & 7, c = t >> 3;  // 32 chunks of 32 blocks
    float hsum = 0.f, msum = 0.f;
    for (int i = c; i < NBLK; i += 32) {
        hsum += hpart[i * 8 + e];
        msum += mpart[i * 8 + e];
    }
    hs[t] = hsum;
    ms[t] = msum;
    __syncthreads();
    if (t < 8) {
        float hh = 0.f, mm = 0.f;
        for (int c2 = 0; c2 < 32; ++c2) { hh += hs[c2 * 8 + t]; mm += ms[c2 * 8 + t]; }
        hs[t] = hh;
        ms[t] = mm;
    }
    __syncthreads();
    if (t == 0) {
        float loss = 0.f;
        for (int e2 = 0; e2 < 8; ++e2)
            loss += (hs[e2] / 4096.f) * (ms[e2] / 4096.f);
        out[2 * BB + 8 * BB] = loss * 8.f;  // index 40960
    }
}

extern "C" void kernel_launch(void* const* d_in, const int* in_sizes, int n_in,
                              void* d_out, int out_size, void* d_ws, size_t ws_size,
                              hipStream_t stream) {
    const float* x     = (const float*)d_in[0];
    const float* noise = (const float*)d_in[1];
    const float* gw    = (const float*)d_in[2];
    const float* gb    = (const float*)d_in[3];
    const float* ew    = (const float*)d_in[4];
    const float* eb    = (const float*)d_in[5];
    float* out = (float*)d_out;
    float* ws  = (float*)d_ws;

    main_kernel<<<NBLK, 256, 0, stream>>>(x, noise, gw, gb, ew, eb, out,
                                          ws + WS_H, ws + WS_M);
    loss_kernel<<<1, 256, 0, stream>>>(ws + WS_H, ws + WS_M, out);
}